// Round 1
// baseline (12343.703 us; speedup 1.0000x reference)
//
#include <hip/hip_runtime.h>
#include <hip/hip_bf16.h>

// CTRNN on MI355X.
//   out layout (fp32): output[512][128][1024] | hidden[128][1024] | ip[512][128][1024]
// Phase 1: cvt weights fp32->bf16 (ws)
// Phase 2: ip = x @ W_in^T + b_in   (bf16 MFMA, fp32 out -> d_out seg3)
// Phase 3: persistent recurrent kernel, 128 blocks = 8 batch-tiles x 16 H-tiles.
//          W_hh slice lives in VGPRs for all 512 steps; h exchanged via depth-2
//          global ring + per-(t,batch-tile) release counters (16 producers).

typedef __attribute__((ext_vector_type(8))) short short8;
typedef __attribute__((ext_vector_type(4))) float f32x4;

#define S_LEN 512
#define BATCH 128
#define IN_DIM 512
#define HID 1024

__device__ __forceinline__ ushort f2bf(float f) {
    __hip_bfloat16 h = __float2bfloat16(f);
    return *reinterpret_cast<ushort*>(&h);
}

// ---------------- weight conversion ----------------
__global__ void cvt_weights(const float* __restrict__ whh, const float* __restrict__ win,
                            ushort* __restrict__ whh_bf, ushort* __restrict__ win_bf) {
    int i = blockIdx.x * blockDim.x + threadIdx.x;
    if (i < HID * HID) whh_bf[i] = f2bf(whh[i]);
    if (i < HID * IN_DIM) win_bf[i] = f2bf(win[i]);
}

// ---------------- input projection GEMM ----------------
// C[M=65536][N=1024] = A[M][K=512] * B[N][K]^T + b_in, tiles 64x64, K-chunk 32.
// 256 threads = 4 waves; wave w owns rows [w*16, w*16+16) x all 64 cols.
__global__ __launch_bounds__(256) void ip_gemm(const float* __restrict__ x,
                                               const ushort* __restrict__ winb,
                                               const float* __restrict__ b_in,
                                               float* __restrict__ ip) {
    __shared__ __align__(16) ushort As[64 * 32];
    __shared__ __align__(16) ushort Bs[64 * 32];
    const int tid  = threadIdx.x;
    const int lane = tid & 63;
    const int w    = tid >> 6;
    const int mt   = blockIdx.x >> 4;   // 1024 M-tiles
    const int nt   = blockIdx.x & 15;   // 16 N-tiles
    const long Mbase = (long)mt * 64;
    const int  Nbase = nt * 64;

    // staging: thread -> row sr=tid>>2 (0..63), k-offset sk=(tid&3)*8
    const int sr = tid >> 2;
    const int sk = (tid & 3) * 8;

    f32x4 acc0 = {0,0,0,0}, acc1 = {0,0,0,0}, acc2 = {0,0,0,0}, acc3 = {0,0,0,0};

    const int ar    = w * 16 + (lane & 15);
    const int kb    = ((lane >> 4) * 8) * 2;                    // k byte offset within 32-chunk row
    const int aoff  = (ar * 64 + kb) ^ ((ar & 7) << 4);
    const int boff  = ((lane & 15) * 64 + kb) ^ (((lane & 15) & 7) << 4);
    const int soff  = (sr * 64 + sk * 2) ^ ((sr & 7) << 4);

    for (int kc = 0; kc < IN_DIM; kc += 32) {
        const float* ap = x + (Mbase + sr) * IN_DIM + kc + sk;
        f32x4 av0 = *(const f32x4*)ap;
        f32x4 av1 = *(const f32x4*)(ap + 4);
        short8 bv = *(const short8*)(winb + (size_t)(Nbase + sr) * IN_DIM + kc + sk);
        short8 av;
#pragma unroll
        for (int j = 0; j < 4; ++j) {
            av[j]     = (short)f2bf(av0[j]);
            av[4 + j] = (short)f2bf(av1[j]);
        }
        __syncthreads();   // prior iteration's LDS reads complete
        *(short8*)((char*)As + soff) = av;
        *(short8*)((char*)Bs + soff) = bv;
        __syncthreads();

        short8 a  = *(const short8*)((char*)As + aoff);
        short8 b0 = *(const short8*)((char*)Bs + boff);
        short8 b1 = *(const short8*)((char*)Bs + boff + 1024);
        short8 b2 = *(const short8*)((char*)Bs + boff + 2048);
        short8 b3 = *(const short8*)((char*)Bs + boff + 3072);
        acc0 = __builtin_amdgcn_mfma_f32_16x16x32_bf16(a, b0, acc0, 0, 0, 0);
        acc1 = __builtin_amdgcn_mfma_f32_16x16x32_bf16(a, b1, acc1, 0, 0, 0);
        acc2 = __builtin_amdgcn_mfma_f32_16x16x32_bf16(a, b2, acc2, 0, 0, 0);
        acc3 = __builtin_amdgcn_mfma_f32_16x16x32_bf16(a, b3, acc3, 0, 0, 0);
    }

    // epilogue: C/D layout col=lane&15, row=(lane>>4)*4+j  [measured m89/m91]
    const int nl   = lane & 15;
    const int mrow = w * 16 + (lane >> 4) * 4;
    const float bi0 = b_in[Nbase + nl];
    const float bi1 = b_in[Nbase + 16 + nl];
    const float bi2 = b_in[Nbase + 32 + nl];
    const float bi3 = b_in[Nbase + 48 + nl];
#pragma unroll
    for (int j = 0; j < 4; ++j) {
        float* op = ip + (Mbase + mrow + j) * HID + Nbase + nl;
        op[0]  = acc0[j] + bi0;
        op[16] = acc1[j] + bi1;
        op[32] = acc2[j] + bi2;
        op[48] = acc3[j] + bi3;
    }
}

// ---------------- persistent recurrent kernel ----------------
// grid = 128 blocks: bi = blockIdx&7 (batch tile of 16), ni = blockIdx>>3 (64 H cols).
// Per block: W_hh[ni*64..+64][0..1024) bf16 in VGPRs (short8 wf[32] per lane).
// h ring: hbuf[2][128][1024] bf16. flags[t*8+bi] counts producers (16 per row-group).
__global__ __launch_bounds__(256, 1) void ctrnn_rec(const ushort* __restrict__ whh_bf,
                                                    const float* __restrict__ b_hh,
                                                    const float* __restrict__ ip,
                                                    float* __restrict__ out,
                                                    float* __restrict__ hidden,
                                                    ushort* __restrict__ hbuf,
                                                    int* __restrict__ flags) {
    const int tid  = threadIdx.x;
    const int lane = tid & 63;
    const int w    = tid >> 6;
    const int bi   = blockIdx.x & 7;
    const int ni   = blockIdx.x >> 3;

    __shared__ __align__(16) ushort As[16 * 1024];  // 32 KB staged h rows

    const int ncol = lane & 15;
    const int n_g  = ni * 64 + w * 16 + ncol;       // global H column this lane owns (C col)
    const int kgrp = (lane >> 4) * 8;               // k sub-offset within 32-chunk

    // W_hh fragments: wf[kk] = W[n_g][kk*32+kgrp .. +8]  (B operand: col=lane&15, k by group)
    short8 wf[32];
#pragma unroll
    for (int kk = 0; kk < 32; ++kk)
        wf[kk] = *(const short8*)(whh_bf + (size_t)n_g * HID + kk * 32 + kgrp);

    const float bias = b_hh[n_g];
    f32x4 hprev = {0, 0, 0, 0};

    // staging map: row r = tid&15, col chunk = (tid>>4)*64 (conflict-free with swizzle)
    const int sr = tid & 15;
    const int sc = (tid >> 4) * 64;

    const int  arow  = lane & 15;
    const int  arxor = (arow & 7) << 4;

    for (int t = 0; t < S_LEN; ++t) {
        const float* ipt = ip + (size_t)t * BATCH * HID;
        // prefetch xt (independent of flags/h)
        f32x4 xtv;
#pragma unroll
        for (int j = 0; j < 4; ++j) {
            int b_g = bi * 16 + (lane >> 4) * 4 + j;
            xtv[j] = ipt[(size_t)b_g * HID + n_g];
        }

        f32x4 ac0 = {0,0,0,0}, ac1 = {0,0,0,0}, ac2 = {0,0,0,0}, ac3 = {0,0,0,0};
        if (t > 0) {
            if (tid == 0) {
                long spin = 0;
                while (__hip_atomic_load(&flags[(t - 1) * 8 + bi], __ATOMIC_ACQUIRE,
                                         __HIP_MEMORY_SCOPE_AGENT) < 16) {
                    __builtin_amdgcn_s_sleep(1);
                    if (++spin > (1L << 22)) break;   // bail out instead of hanging
                }
            }
            __syncthreads();
            __threadfence();  // acquire: invalidate stale cached h lines

            // stage h[t-1] rows [bi*16, +16) into LDS (XOR-swizzled)
            const ushort* src = hbuf + (size_t)((t - 1) & 1) * BATCH * HID
                                + (size_t)(bi * 16 + sr) * HID + sc;
#pragma unroll
            for (int i2 = 0; i2 < 8; ++i2) {
                short8 v  = *(const short8*)(src + i2 * 8);
                int   off = (sr * 2048 + (sc + i2 * 8) * 2) ^ ((sr & 7) << 4);
                *(short8*)((char*)As + off) = v;
            }
            __syncthreads();

#define AREAD(kk) (*(const short8*)((char*)As + ((arow * 2048 + ((kk) * 32 + kgrp) * 2) ^ arxor)))
#pragma unroll
            for (int kk = 0; kk < 32; kk += 4) {
                ac0 = __builtin_amdgcn_mfma_f32_16x16x32_bf16(AREAD(kk + 0), wf[kk + 0], ac0, 0, 0, 0);
                ac1 = __builtin_amdgcn_mfma_f32_16x16x32_bf16(AREAD(kk + 1), wf[kk + 1], ac1, 0, 0, 0);
                ac2 = __builtin_amdgcn_mfma_f32_16x16x32_bf16(AREAD(kk + 2), wf[kk + 2], ac2, 0, 0, 0);
                ac3 = __builtin_amdgcn_mfma_f32_16x16x32_bf16(AREAD(kk + 3), wf[kk + 3], ac3, 0, 0, 0);
            }
#undef AREAD
        }

        // epilogue: hnew = relu(xt + Wh + b); h = 0.8*h + 0.2*hnew
        float* outt = out + (size_t)t * BATCH * HID;
        ushort* hb  = hbuf + (size_t)(t & 1) * BATCH * HID;
#pragma unroll
        for (int j = 0; j < 4; ++j) {
            int    b_g = bi * 16 + (lane >> 4) * 4 + j;
            size_t idx = (size_t)b_g * HID + n_g;
            float acc  = (ac0[j] + ac1[j]) + (ac2[j] + ac3[j]);
            float hn   = xtv[j] + acc + bias;
            hn         = hn > 0.0f ? hn : 0.0f;
            float h    = hprev[j] * 0.8f + 0.2f * hn;
            hprev[j]   = h;
            outt[idx]  = h;
            hb[idx]    = f2bf(h);
            if (t == S_LEN - 1) hidden[idx] = h;
        }
        __threadfence();   // make this thread's h stores device-visible
        __syncthreads();   // all threads in block done
        if (tid == 0)
            __hip_atomic_fetch_add(&flags[t * 8 + bi], 1, __ATOMIC_RELEASE,
                                   __HIP_MEMORY_SCOPE_AGENT);
    }
}

extern "C" void kernel_launch(void* const* d_in, const int* in_sizes, int n_in,
                              void* d_out, int out_size, void* d_ws, size_t ws_size,
                              hipStream_t stream) {
    const float* x    = (const float*)d_in[0];
    const float* W_in = (const float*)d_in[1];
    const float* b_in = (const float*)d_in[2];
    const float* W_hh = (const float*)d_in[3];
    const float* b_hh = (const float*)d_in[4];

    float* out    = (float*)d_out;
    float* hidden = out + (size_t)S_LEN * BATCH * HID;
    float* ip     = hidden + (size_t)BATCH * HID;

    char* ws = (char*)d_ws;
    ushort* whh_bf = (ushort*)ws;                                    // 2 MB
    ushort* win_bf = (ushort*)(ws + (size_t)2 * 1024 * 1024);        // 1 MB
    ushort* hbuf   = (ushort*)(ws + (size_t)3 * 1024 * 1024);        // 512 KB
    int*    flags  = (int*)(ws + (size_t)3 * 1024 * 1024 + 512 * 1024);  // 16 KB

    hipMemsetAsync(flags, 0, S_LEN * 8 * sizeof(int), stream);
    cvt_weights<<<4096, 256, 0, stream>>>(W_hh, W_in, whh_bf, win_bf);
    ip_gemm<<<(65536 / 64) * (HID / 64), 256, 0, stream>>>(x, win_bf, b_in, ip);
    ctrnn_rec<<<128, 256, 0, stream>>>(whh_bf, b_hh, ip, out, hidden, hbuf, flags);
}

// Round 2
// 2135.282 us; speedup vs baseline: 5.7808x; 5.7808x over previous
//
#include <hip/hip_runtime.h>
#include <hip/hip_bf16.h>

// CTRNN on MI355X.
//   out layout (fp32): output[512][128][1024] | hidden[128][1024] | ip[512][128][1024]
// Phase 1: cvt weights fp32->bf16 (ws)
// Phase 2: ip = x @ W_in^T + b_in   (bf16 MFMA, fp32 out -> d_out seg3)
// Phase 3: persistent recurrent kernel, 128 blocks = 8 batch-tiles x 16 H-tiles.
//          W_hh slice lives in VGPRs/AGPRs for all 512 steps; h exchanged via a
//          depth-2 ring of cache-BYPASSING (sc0 sc1) stores/loads + per-producer
//          flag words. No threadfence (no L2 writeback), no atomic RMW.

typedef __attribute__((ext_vector_type(8))) short short8;
typedef __attribute__((ext_vector_type(4))) float f32x4;

#define S_LEN 512
#define BATCH 128
#define IN_DIM 512
#define HID 1024

__device__ __forceinline__ ushort f2bf(float f) {
    __hip_bfloat16 h = __float2bfloat16(f);
    return *reinterpret_cast<ushort*>(&h);
}

// ---------------- weight conversion ----------------
__global__ void cvt_weights(const float* __restrict__ whh, const float* __restrict__ win,
                            ushort* __restrict__ whh_bf, ushort* __restrict__ win_bf) {
    int i = blockIdx.x * blockDim.x + threadIdx.x;
    if (i < HID * HID) whh_bf[i] = f2bf(whh[i]);
    if (i < HID * IN_DIM) win_bf[i] = f2bf(win[i]);
}

// ---------------- input projection GEMM ----------------
// C[M=65536][N=1024] = A[M][K=512] * B[N][K]^T + b_in, tiles 64x64, K-chunk 32.
__global__ __launch_bounds__(256) void ip_gemm(const float* __restrict__ x,
                                               const ushort* __restrict__ winb,
                                               const float* __restrict__ b_in,
                                               float* __restrict__ ip) {
    __shared__ __align__(16) ushort As[64 * 32];
    __shared__ __align__(16) ushort Bs[64 * 32];
    const int tid  = threadIdx.x;
    const int lane = tid & 63;
    const int w    = tid >> 6;
    const int mt   = blockIdx.x >> 4;
    const int nt   = blockIdx.x & 15;
    const long Mbase = (long)mt * 64;
    const int  Nbase = nt * 64;

    const int sr = tid >> 2;
    const int sk = (tid & 3) * 8;

    f32x4 acc0 = {0,0,0,0}, acc1 = {0,0,0,0}, acc2 = {0,0,0,0}, acc3 = {0,0,0,0};

    const int ar    = w * 16 + (lane & 15);
    const int kb    = ((lane >> 4) * 8) * 2;
    const int aoff  = (ar * 64 + kb) ^ ((ar & 7) << 4);
    const int boff  = ((lane & 15) * 64 + kb) ^ (((lane & 15) & 7) << 4);
    const int soff  = (sr * 64 + sk * 2) ^ ((sr & 7) << 4);

    for (int kc = 0; kc < IN_DIM; kc += 32) {
        const float* ap = x + (Mbase + sr) * IN_DIM + kc + sk;
        f32x4 av0 = *(const f32x4*)ap;
        f32x4 av1 = *(const f32x4*)(ap + 4);
        short8 bv = *(const short8*)(winb + (size_t)(Nbase + sr) * IN_DIM + kc + sk);
        short8 av;
#pragma unroll
        for (int j = 0; j < 4; ++j) {
            av[j]     = (short)f2bf(av0[j]);
            av[4 + j] = (short)f2bf(av1[j]);
        }
        __syncthreads();
        *(short8*)((char*)As + soff) = av;
        *(short8*)((char*)Bs + soff) = bv;
        __syncthreads();

        short8 a  = *(const short8*)((char*)As + aoff);
        short8 b0 = *(const short8*)((char*)Bs + boff);
        short8 b1 = *(const short8*)((char*)Bs + boff + 1024);
        short8 b2 = *(const short8*)((char*)Bs + boff + 2048);
        short8 b3 = *(const short8*)((char*)Bs + boff + 3072);
        acc0 = __builtin_amdgcn_mfma_f32_16x16x32_bf16(a, b0, acc0, 0, 0, 0);
        acc1 = __builtin_amdgcn_mfma_f32_16x16x32_bf16(a, b1, acc1, 0, 0, 0);
        acc2 = __builtin_amdgcn_mfma_f32_16x16x32_bf16(a, b2, acc2, 0, 0, 0);
        acc3 = __builtin_amdgcn_mfma_f32_16x16x32_bf16(a, b3, acc3, 0, 0, 0);
    }

    const int nl   = lane & 15;
    const int mrow = w * 16 + (lane >> 4) * 4;
    const float bi0 = b_in[Nbase + nl];
    const float bi1 = b_in[Nbase + 16 + nl];
    const float bi2 = b_in[Nbase + 32 + nl];
    const float bi3 = b_in[Nbase + 48 + nl];
#pragma unroll
    for (int j = 0; j < 4; ++j) {
        float* op = ip + (Mbase + mrow + j) * HID + Nbase + nl;
        op[0]  = acc0[j] + bi0;
        op[16] = acc1[j] + bi1;
        op[32] = acc2[j] + bi2;
        op[48] = acc3[j] + bi3;
    }
}

// ---------------- persistent recurrent kernel ----------------
// grid = 128 blocks: bi = blockIdx&7 (batch tile of 16), ni = blockIdx>>3 (64 H cols).
// flags[t*128 + bi*16 + ni] = 1 when block (bi,ni) finished step t.
__global__ __launch_bounds__(256, 1) void ctrnn_rec(const ushort* __restrict__ whh_bf,
                                                    const float* __restrict__ b_hh,
                                                    const float* __restrict__ ip,
                                                    float* __restrict__ out,
                                                    float* __restrict__ hidden,
                                                    ushort* __restrict__ hbuf,
                                                    int* __restrict__ flags) {
    const int tid  = threadIdx.x;
    const int lane = tid & 63;
    const int w    = tid >> 6;
    const int bi   = blockIdx.x & 7;
    const int ni   = blockIdx.x >> 3;

    __shared__ __align__(16) ushort As[16 * 1024];  // 32 KB staged h rows

    const int ncol = lane & 15;
    const int n_g  = ni * 64 + w * 16 + ncol;
    const int kgrp = (lane >> 4) * 8;

    // W_hh fragments: wf[kk] = W[n_g][kk*32+kgrp .. +8]
    short8 wf[32];
#pragma unroll
    for (int kk = 0; kk < 32; ++kk)
        wf[kk] = *(const short8*)(whh_bf + (size_t)n_g * HID + kk * 32 + kgrp);

    const float bias = b_hh[n_g];
    f32x4 hprev = {0, 0, 0, 0};

    const int sr = tid & 15;          // staging row
    const int sc = (tid >> 4) * 64;   // staging col chunk

    const int  arow  = lane & 15;
    const int  arxor = (arow & 7) << 4;

    for (int t = 0; t < S_LEN; ++t) {
        const float* ipt = ip + (size_t)t * BATCH * HID;
        // prefetch xt (independent of flags/h)
        f32x4 xtv;
#pragma unroll
        for (int j = 0; j < 4; ++j) {
            int b_g = bi * 16 + (lane >> 4) * 4 + j;
            xtv[j] = ipt[(size_t)b_g * HID + n_g];
        }

        f32x4 ac0 = {0,0,0,0}, ac1 = {0,0,0,0}, ac2 = {0,0,0,0}, ac3 = {0,0,0,0};
        if (t > 0) {
            // ---- poll per-producer flags (all waves; lanes 0-15 carry info) ----
            {
                const int* fl = flags + (size_t)(t - 1) * 128 + bi * 16 + (lane & 15);
                int  ok   = 0;
                long spin = 0;
                while (!ok) {
                    int v = __hip_atomic_load(fl, __ATOMIC_RELAXED, __HIP_MEMORY_SCOPE_AGENT);
                    ok = __all(v != 0);
                    if (!ok) {
                        __builtin_amdgcn_s_sleep(1);
                        if (++spin > (1L << 21)) break;  // safety bail-out
                    }
                }
            }

            // ---- bypass-load h[t-1] rows (coherent path), stage to LDS ----
            const ushort* src = hbuf + (size_t)((t - 1) & 1) * BATCH * HID
                                + (size_t)(bi * 16 + sr) * HID + sc;
            short8 hv[8];
#pragma unroll
            for (int i2 = 0; i2 < 8; ++i2)
                asm volatile("global_load_dwordx4 %0, %1, off sc0 sc1"
                             : "=v"(hv[i2]) : "v"(src + i2 * 8) : "memory");
            asm volatile("s_waitcnt vmcnt(0)" ::: "memory");
            __builtin_amdgcn_sched_barrier(0);
#pragma unroll
            for (int i2 = 0; i2 < 8; ++i2) {
                int off = (sr * 2048 + (sc + i2 * 8) * 2) ^ ((sr & 7) << 4);
                *(short8*)((char*)As + off) = hv[i2];
            }
            __syncthreads();

#define AREAD(kk) (*(const short8*)((char*)As + ((arow * 2048 + ((kk) * 32 + kgrp) * 2) ^ arxor)))
#pragma unroll
            for (int kk = 0; kk < 32; kk += 4) {
                ac0 = __builtin_amdgcn_mfma_f32_16x16x32_bf16(AREAD(kk + 0), wf[kk + 0], ac0, 0, 0, 0);
                ac1 = __builtin_amdgcn_mfma_f32_16x16x32_bf16(AREAD(kk + 1), wf[kk + 1], ac1, 0, 0, 0);
                ac2 = __builtin_amdgcn_mfma_f32_16x16x32_bf16(AREAD(kk + 2), wf[kk + 2], ac2, 0, 0, 0);
                ac3 = __builtin_amdgcn_mfma_f32_16x16x32_bf16(AREAD(kk + 3), wf[kk + 3], ac3, 0, 0, 0);
            }
#undef AREAD
        }

        // epilogue: hnew = relu(xt + Wh + b); h = 0.8*h + 0.2*hnew
        float* outt = out + (size_t)t * BATCH * HID;
        ushort* hb  = hbuf + (size_t)(t & 1) * BATCH * HID;
#pragma unroll
        for (int j = 0; j < 4; ++j) {
            int    b_g = bi * 16 + (lane >> 4) * 4 + j;
            size_t idx = (size_t)b_g * HID + n_g;
            float acc  = (ac0[j] + ac1[j]) + (ac2[j] + ac3[j]);
            float hn   = xtv[j] + acc + bias;
            hn         = hn > 0.0f ? hn : 0.0f;
            float h    = hprev[j] * 0.8f + 0.2f * hn;
            hprev[j]   = h;
            outt[idx]  = h;
            ushort hb16 = f2bf(h);
            asm volatile("global_store_short %0, %1, off sc0 sc1"
                         :: "v"(hb + idx), "v"(hb16) : "memory");
            if (t == S_LEN - 1) hidden[idx] = h;
        }
        asm volatile("s_waitcnt vmcnt(0)" ::: "memory");  // bypass stores committed
        __syncthreads();                                   // whole block done
        if (tid == 0)
            __hip_atomic_store(&flags[(size_t)t * 128 + bi * 16 + ni], 1,
                               __ATOMIC_RELAXED, __HIP_MEMORY_SCOPE_AGENT);
    }
}

extern "C" void kernel_launch(void* const* d_in, const int* in_sizes, int n_in,
                              void* d_out, int out_size, void* d_ws, size_t ws_size,
                              hipStream_t stream) {
    const float* x    = (const float*)d_in[0];
    const float* W_in = (const float*)d_in[1];
    const float* b_in = (const float*)d_in[2];
    const float* W_hh = (const float*)d_in[3];
    const float* b_hh = (const float*)d_in[4];

    float* out    = (float*)d_out;
    float* hidden = out + (size_t)S_LEN * BATCH * HID;
    float* ip     = hidden + (size_t)BATCH * HID;

    char* ws = (char*)d_ws;
    ushort* whh_bf = (ushort*)ws;                                    // 2 MB
    ushort* win_bf = (ushort*)(ws + (size_t)2 * 1024 * 1024);        // 1 MB (dead after ip_gemm)
    ushort* hbuf   = (ushort*)(ws + (size_t)3 * 1024 * 1024);        // 512 KB
    int*    flags  = (int*)win_bf;                                   // reuse win_bf region (256 KB)

    cvt_weights<<<4096, 256, 0, stream>>>(W_hh, W_in, whh_bf, win_bf);
    ip_gemm<<<(65536 / 64) * (HID / 64), 256, 0, stream>>>(x, win_bf, b_in, ip);
    // win_bf is dead now; reuse its storage for flags (S_LEN*128 ints = 256 KB)
    hipMemsetAsync(flags, 0, (size_t)S_LEN * 128 * sizeof(int), stream);
    ctrnn_rec<<<128, 256, 0, stream>>>(whh_bf, b_hh, ip, out, hidden, hbuf, flags);
}

// Round 3
// 1912.037 us; speedup vs baseline: 6.4558x; 1.1168x over previous
//
#include <hip/hip_runtime.h>
#include <hip/hip_bf16.h>

// CTRNN on MI355X.
//   out layout (fp32): output[512][128][1024] | hidden[128][1024] | ip[512][128][1024]
// Phase 1: cvt W_in fp32->bf16 (ws)
// Phase 2: ip = x @ W_in^T + b_in   (bf16 MFMA, fp32 out -> d_out seg3)
// Phase 3: persistent recurrent kernel, 128 blocks = 8 batch-tiles x 16 H-tiles.
//          W_hh slice in VGPRs/AGPRs (converted in-kernel); h exchanged via
//          depth-2 bypass ring; per-WAVE 16B-padded flags (no contention, no
//          pre-flag barrier); per-wave pipelined consume; wide (8B) h stores.

typedef __attribute__((ext_vector_type(8))) short short8;
typedef __attribute__((ext_vector_type(4))) float f32x4;

#define S_LEN 512
#define BATCH 128
#define IN_DIM 512
#define HID 1024

__device__ __forceinline__ ushort f2bf(float f) {
    __hip_bfloat16 h = __float2bfloat16(f);
    return *reinterpret_cast<ushort*>(&h);
}

// ---------------- W_in conversion ----------------
__global__ void cvt_win(const float* __restrict__ win, ushort* __restrict__ win_bf) {
    int i = blockIdx.x * blockDim.x + threadIdx.x;
    if (i < HID * IN_DIM) win_bf[i] = f2bf(win[i]);
}

// ---------------- input projection GEMM ----------------
__global__ __launch_bounds__(256) void ip_gemm(const float* __restrict__ x,
                                               const ushort* __restrict__ winb,
                                               const float* __restrict__ b_in,
                                               float* __restrict__ ip) {
    __shared__ __align__(16) ushort As[64 * 32];
    __shared__ __align__(16) ushort Bs[64 * 32];
    const int tid  = threadIdx.x;
    const int lane = tid & 63;
    const int w    = tid >> 6;
    const int mt   = blockIdx.x >> 4;
    const int nt   = blockIdx.x & 15;
    const long Mbase = (long)mt * 64;
    const int  Nbase = nt * 64;

    const int sr = tid >> 2;
    const int sk = (tid & 3) * 8;

    f32x4 acc0 = {0,0,0,0}, acc1 = {0,0,0,0}, acc2 = {0,0,0,0}, acc3 = {0,0,0,0};

    const int ar    = w * 16 + (lane & 15);
    const int kb    = ((lane >> 4) * 8) * 2;
    const int aoff  = (ar * 64 + kb) ^ ((ar & 7) << 4);
    const int boff  = ((lane & 15) * 64 + kb) ^ (((lane & 15) & 7) << 4);
    const int soff  = (sr * 64 + sk * 2) ^ ((sr & 7) << 4);

    for (int kc = 0; kc < IN_DIM; kc += 32) {
        const float* ap = x + (Mbase + sr) * IN_DIM + kc + sk;
        f32x4 av0 = *(const f32x4*)ap;
        f32x4 av1 = *(const f32x4*)(ap + 4);
        short8 bv = *(const short8*)(winb + (size_t)(Nbase + sr) * IN_DIM + kc + sk);
        short8 av;
#pragma unroll
        for (int j = 0; j < 4; ++j) {
            av[j]     = (short)f2bf(av0[j]);
            av[4 + j] = (short)f2bf(av1[j]);
        }
        __syncthreads();
        *(short8*)((char*)As + soff) = av;
        *(short8*)((char*)Bs + soff) = bv;
        __syncthreads();

        short8 a  = *(const short8*)((char*)As + aoff);
        short8 b0 = *(const short8*)((char*)Bs + boff);
        short8 b1 = *(const short8*)((char*)Bs + boff + 1024);
        short8 b2 = *(const short8*)((char*)Bs + boff + 2048);
        short8 b3 = *(const short8*)((char*)Bs + boff + 3072);
        acc0 = __builtin_amdgcn_mfma_f32_16x16x32_bf16(a, b0, acc0, 0, 0, 0);
        acc1 = __builtin_amdgcn_mfma_f32_16x16x32_bf16(a, b1, acc1, 0, 0, 0);
        acc2 = __builtin_amdgcn_mfma_f32_16x16x32_bf16(a, b2, acc2, 0, 0, 0);
        acc3 = __builtin_amdgcn_mfma_f32_16x16x32_bf16(a, b3, acc3, 0, 0, 0);
    }

    const int nl   = lane & 15;
    const int mrow = w * 16 + (lane >> 4) * 4;
    const float bi0 = b_in[Nbase + nl];
    const float bi1 = b_in[Nbase + 16 + nl];
    const float bi2 = b_in[Nbase + 32 + nl];
    const float bi3 = b_in[Nbase + 48 + nl];
#pragma unroll
    for (int j = 0; j < 4; ++j) {
        float* op = ip + (Mbase + mrow + j) * HID + Nbase + nl;
        op[0]  = acc0[j] + bi0;
        op[16] = acc1[j] + bi1;
        op[32] = acc2[j] + bi2;
        op[48] = acc3[j] + bi3;
    }
}

// ---------------- persistent recurrent kernel ----------------
// grid = 128 blocks: bi = blockIdx&7, ni = blockIdx>>3.
// flags[t][bi][p][w] (16B-padded ints): wave w of block (bi,p) done with step t.
__global__ __launch_bounds__(256, 1) void ctrnn_rec(const float* __restrict__ whh,
                                                    const float* __restrict__ b_hh,
                                                    const float* __restrict__ ip,
                                                    float* __restrict__ out,
                                                    float* __restrict__ hidden,
                                                    ushort* __restrict__ hbuf,
                                                    int* __restrict__ flags) {
    const int tid  = threadIdx.x;
    const int lane = tid & 63;
    const int w    = tid >> 6;
    const int w4   = w * 4;
    const int bi   = blockIdx.x & 7;
    const int ni   = blockIdx.x >> 3;

    __shared__ __align__(16) ushort As[2][16 * 1024];  // 64 KB, h double buffer
    __shared__ __align__(16) float  tile[16][68];       // transpose tile (padded)

    const int ncol = lane & 15;
    const int n_g  = ni * 64 + w * 16 + ncol;
    const int kgrp = (lane >> 4) * 8;

    // W_hh fragments converted from fp32 at startup
    short8 wf[32];
#pragma unroll
    for (int kk = 0; kk < 32; ++kk) {
        const float* wp = whh + (size_t)n_g * HID + kk * 32 + kgrp;
        f32x4 w0 = *(const f32x4*)wp;
        f32x4 w1 = *(const f32x4*)(wp + 4);
        short8 f;
#pragma unroll
        for (int j = 0; j < 4; ++j) {
            f[j]     = (short)f2bf(w0[j]);
            f[4 + j] = (short)f2bf(w1[j]);
        }
        wf[kk] = f;
    }

    const float bias = b_hh[n_g];
    f32x4 hprev = {0, 0, 0, 0};

    const int r8 = lane >> 3, c8 = lane & 7;   // staging lane map
    const int arow  = lane & 15;
    const int arxor = (arow & 7) << 4;
    const int tr = tid >> 4, tc4 = (tid & 15) * 4;  // transpose-read map

    for (int t = 0; t < S_LEN; ++t) {
        const float* ipt = ip + (size_t)t * BATCH * HID;
        f32x4 xtv;
#pragma unroll
        for (int j = 0; j < 4; ++j) {
            int b_g = bi * 16 + (lane >> 4) * 4 + j;
            xtv[j] = ipt[(size_t)b_g * HID + n_g];
        }

        f32x4 ac0 = {0,0,0,0}, ac1 = {0,0,0,0}, ac2 = {0,0,0,0}, ac3 = {0,0,0,0};
        if (t > 0) {
            const int slot = (t - 1) & 1;
            // ---- per-wave poll: this wave's 4 producers x 4 waves = 16 flag words ----
            {
                const int* fl = flags + ((((size_t)(t - 1) * 8 + bi) * 64) + w4 * 4 + (lane & 15)) * 4;
                int  v = 0;
                long spin = 0;
                do {
                    asm volatile("global_load_dword %0, %1, off sc0 sc1\n\ts_waitcnt vmcnt(0)"
                                 : "=v"(v) : "v"(fl) : "memory");
                    if (__all(v != 0)) break;
                    __builtin_amdgcn_s_sleep(1);
                } while (++spin < (1L << 20));
            }

            // ---- stage this wave's 4 producers (2KB each) into LDS ----
            const ushort* hsrc = hbuf + (size_t)slot * BATCH * HID;
            ushort* Asb = &As[slot][0];
            short8 h0, h1, h2, h3, h4, h5, h6, h7;
#define LD(reg, q, i)                                                                  \
            asm volatile("global_load_dwordx4 %0, %1, off sc0 sc1" : "=v"(reg)         \
                : "v"(hsrc + (size_t)(bi * 16 + (i) * 8 + r8) * HID + (w4 + (q)) * 64 + c8 * 8) \
                : "memory")
            LD(h0, 0, 0); LD(h1, 0, 1); LD(h2, 1, 0); LD(h3, 1, 1);
            LD(h4, 2, 0); LD(h5, 2, 1); LD(h6, 3, 0); LD(h7, 3, 1);
#undef LD
            asm volatile("s_waitcnt vmcnt(0)" ::: "memory");
            __builtin_amdgcn_sched_barrier(0);
#define ST(reg, q, i)                                                                   \
            { int rl = (i) * 8 + r8;                                                    \
              int off = (rl * 2048 + ((w4 + (q)) * 64 + c8 * 8) * 2) ^ ((rl & 7) << 4); \
              *(short8*)((char*)Asb + off) = reg; }
            ST(h0, 0, 0); ST(h1, 0, 1); ST(h2, 1, 0); ST(h3, 1, 1);
            ST(h4, 2, 0); ST(h5, 2, 1); ST(h6, 3, 0); ST(h7, 3, 1);
#undef ST
            __syncthreads();

#define AREAD(kk) (*(const short8*)((char*)Asb + ((arow * 2048 + ((kk) * 32 + kgrp) * 2) ^ arxor)))
#pragma unroll
            for (int kk = 0; kk < 32; kk += 4) {
                ac0 = __builtin_amdgcn_mfma_f32_16x16x32_bf16(AREAD(kk + 0), wf[kk + 0], ac0, 0, 0, 0);
                ac1 = __builtin_amdgcn_mfma_f32_16x16x32_bf16(AREAD(kk + 1), wf[kk + 1], ac1, 0, 0, 0);
                ac2 = __builtin_amdgcn_mfma_f32_16x16x32_bf16(AREAD(kk + 2), wf[kk + 2], ac2, 0, 0, 0);
                ac3 = __builtin_amdgcn_mfma_f32_16x16x32_bf16(AREAD(kk + 3), wf[kk + 3], ac3, 0, 0, 0);
            }
#undef AREAD
        }

        // ---- epilogue: h update in C-frag regs -> LDS transpose ----
#pragma unroll
        for (int j = 0; j < 4; ++j) {
            float acc = (ac0[j] + ac1[j]) + (ac2[j] + ac3[j]);
            float hn  = xtv[j] + acc + bias;
            hn        = hn > 0.0f ? hn : 0.0f;
            float h   = hprev[j] * 0.8f + 0.2f * hn;
            hprev[j]  = h;
            tile[(lane >> 4) * 4 + j][w * 16 + ncol] = h;
        }
        __syncthreads();

        // ---- wide read-back: thread owns (row tr, cols tc4..tc4+3) of 16x64 tile ----
        f32x4 hw = *(const f32x4*)&tile[tr][tc4];
        uint2 pk;
        pk.x = (uint)f2bf(hw[0]) | ((uint)f2bf(hw[1]) << 16);
        pk.y = (uint)f2bf(hw[2]) | ((uint)f2bf(hw[3]) << 16);
        ushort* hdst = hbuf + (size_t)(t & 1) * BATCH * HID
                       + (size_t)(bi * 16 + tr) * HID + ni * 64 + tc4;
        asm volatile("global_store_dwordx2 %0, %1, off sc0 sc1" :: "v"(hdst), "v"(pk) : "memory");
        asm volatile("s_waitcnt vmcnt(0)" ::: "memory");
        // per-wave flag (own wave's stores drained by the vmcnt above)
        if (lane == 0) {
            int one = 1;
            int* fdst = flags + ((((size_t)t * 8 + bi) * 64) + ni * 4 + w) * 4;
            asm volatile("global_store_dword %0, %1, off sc0 sc1" :: "v"(fdst), "v"(one) : "memory");
        }
        // plain cached wide stores (off the critical path)
        float* od = out + (size_t)t * BATCH * HID + (size_t)(bi * 16 + tr) * HID + ni * 64 + tc4;
        *(f32x4*)od = hw;
        if (t == S_LEN - 1) {
            float* hd = hidden + (size_t)(bi * 16 + tr) * HID + ni * 64 + tc4;
            *(f32x4*)hd = hw;
        }
    }
}

extern "C" void kernel_launch(void* const* d_in, const int* in_sizes, int n_in,
                              void* d_out, int out_size, void* d_ws, size_t ws_size,
                              hipStream_t stream) {
    const float* x    = (const float*)d_in[0];
    const float* W_in = (const float*)d_in[1];
    const float* b_in = (const float*)d_in[2];
    const float* W_hh = (const float*)d_in[3];
    const float* b_hh = (const float*)d_in[4];

    float* out    = (float*)d_out;
    float* hidden = out + (size_t)S_LEN * BATCH * HID;
    float* ip     = hidden + (size_t)BATCH * HID;

    char* ws = (char*)d_ws;
    ushort* win_bf = (ushort*)ws;                                 // 1 MB
    ushort* hbuf   = (ushort*)(ws + (size_t)1 * 1024 * 1024);     // 512 KB
    int*    flags  = (int*)(ws + (size_t)2 * 1024 * 1024);        // 4 MB (512*8*64 waves, 16B pad)

    cvt_win<<<(HID * IN_DIM) / 256, 256, 0, stream>>>(W_in, win_bf);
    ip_gemm<<<(65536 / 64) * (HID / 64), 256, 0, stream>>>(x, win_bf, b_in, ip);
    hipMemsetAsync(flags, 0, (size_t)S_LEN * 8 * 64 * 4 * sizeof(int), stream);
    ctrnn_rec<<<128, 256, 0, stream>>>(W_hh, b_hh, ip, out, hidden, hbuf, flags);
}